// Round 1
// baseline (1357.687 us; speedup 1.0000x reference)
//
#include <hip/hip_runtime.h>

#define T_TOK 16384
#define DMODEL 1024
#define DFF 4096
#define NEXP 8
#define BM 128
#define BN 128
#define BK 32
#define LDA 40   // BK + 8 bf16 pad
#define LDB 40

typedef __bf16 bf16x8 __attribute__((ext_vector_type(8)));
typedef float f32x4 __attribute__((ext_vector_type(4)));

__device__ __forceinline__ float gelu_f(float x) {
  // jax.nn.gelu approximate=True (tanh form); overflow-safe tanh via exp
  float u = 0.7978845608028654f * (x + 0.044715f * x * x * x);
  float e = __expf(2.0f * u);
  float th = 1.0f - 2.0f / (e + 1.0f);
  return 0.5f * x * (1.0f + th);
}

// ---------------- routing ----------------
__global__ void k_init(int* counts, int* cursors, int* bucket, int n) {
  int i = blockIdx.x * blockDim.x + threadIdx.x;
  if (i < n) bucket[i] = -1;
  if (i < NEXP) { counts[i] = 0; cursors[i] = 0; }
}

__global__ void k_hist(const int* __restrict__ idx, int* counts) {
  int t = blockIdx.x * blockDim.x + threadIdx.x;
  if (t < T_TOK) atomicAdd(&counts[idx[t]], 1);
}

__global__ void k_scan(const int* __restrict__ counts, int* po) {
  if (threadIdx.x == 0 && blockIdx.x == 0) {
    int acc = 0;
    for (int e = 0; e < NEXP; e++) {
      po[e] = acc;
      acc += ((counts[e] + BM - 1) / BM) * BM;  // pad each expert to BM multiple
    }
    po[NEXP] = acc;
  }
}

__global__ void k_scatter(const int* __restrict__ idx, const int* __restrict__ po,
                          int* cursors, int* bucket) {
  int t = blockIdx.x * blockDim.x + threadIdx.x;
  if (t < T_TOK) {
    int e = idx[t];
    int p = atomicAdd(&cursors[e], 1);
    bucket[po[e] + p] = t;
  }
}

// ---------------- GEMM1: H = gelu(X[bucket] @ W1[e] + b1[e]) ----------------
__global__ __launch_bounds__(256, 2) void k_gemm1(
    const float* __restrict__ X, const float* __restrict__ W1,
    const float* __restrict__ b1, const int* __restrict__ bucket,
    const int* __restrict__ po, __bf16* __restrict__ H, int base_row)
{
  __shared__ __bf16 As[BM * LDA];
  __shared__ __bf16 Bs[BN * LDB];   // transposed: [n][k]
  __shared__ int toks[BM];

  const int tid = threadIdx.x;
  const int total = po[NEXP];
  const int row0 = base_row + (int)blockIdx.x * BM;
  if (row0 >= total) return;
  const int nb0 = (int)blockIdx.y * BN;

  int e = 0;
#pragma unroll
  for (int k = 1; k < NEXP; k++) e = (row0 >= po[k]) ? k : e;
  const float* __restrict__ W = W1 + (size_t)e * DMODEL * DFF;

  if (tid < BM) toks[tid] = bucket[row0 + tid];
  __syncthreads();

  f32x4 acc[4][4];
#pragma unroll
  for (int i = 0; i < 4; i++)
#pragma unroll
    for (int j = 0; j < 4; j++) acc[i][j] = (f32x4)0.0f;

  const int wave = tid >> 6;
  const int lane = tid & 63;
  const int wm = (wave & 1) * 64;
  const int wn = (wave >> 1) * 64;
  const int lm = lane & 15;
  const int lq = lane >> 4;

  const int bn = tid & 127;          // B staging: this thread owns column nb0+bn
  const int bkh = (tid >> 7) * 16;   // and k-rows [bkh, bkh+16)

  for (int k0 = 0; k0 < DMODEL; k0 += BK) {
    // stage A: gathered x rows, fp32 -> bf16
#pragma unroll
    for (int i = 0; i < 4; i++) {
      int idx = tid + i * 256;
      int row = idx >> 3, kq = idx & 7;
      int t = toks[row];
      float4 v = {0.f, 0.f, 0.f, 0.f};
      if (t >= 0) v = *(const float4*)(X + (size_t)t * DMODEL + k0 + kq * 4);
      union { __bf16 h[4]; uint2 u; } cv;
      cv.h[0] = (__bf16)v.x; cv.h[1] = (__bf16)v.y;
      cv.h[2] = (__bf16)v.z; cv.h[3] = (__bf16)v.w;
      *(uint2*)&As[row * LDA + kq * 4] = cv.u;
    }
    // stage B transposed: column-strip (coalesced across lanes), contiguous LDS writes
    {
      const float* src = W + (size_t)(k0 + bkh) * DFF + nb0 + bn;
      bf16x8 b0, b1v;
#pragma unroll
      for (int kk = 0; kk < 8; kk++) b0[kk] = (__bf16)src[(size_t)kk * DFF];
#pragma unroll
      for (int kk = 0; kk < 8; kk++) b1v[kk] = (__bf16)src[(size_t)(kk + 8) * DFF];
      *(bf16x8*)&Bs[bn * LDB + bkh] = b0;
      *(bf16x8*)&Bs[bn * LDB + bkh + 8] = b1v;
    }
    __syncthreads();

    bf16x8 af[4], bfr[4];
#pragma unroll
    for (int i = 0; i < 4; i++)
      af[i] = *(const bf16x8*)&As[(wm + i * 16 + lm) * LDA + lq * 8];
#pragma unroll
    for (int j = 0; j < 4; j++)
      bfr[j] = *(const bf16x8*)&Bs[(wn + j * 16 + lm) * LDB + lq * 8];
#pragma unroll
    for (int i = 0; i < 4; i++)
#pragma unroll
      for (int j = 0; j < 4; j++)
        acc[i][j] = __builtin_amdgcn_mfma_f32_16x16x32_bf16(af[i], bfr[j], acc[i][j], 0, 0, 0);
    __syncthreads();
  }

  const float* __restrict__ b1e = b1 + e * DFF;
  const int hbase = (int)blockIdx.x * BM;
#pragma unroll
  for (int j = 0; j < 4; j++) {
    const int col = nb0 + wn + j * 16 + lm;
    const float bias = b1e[col];
#pragma unroll
    for (int i = 0; i < 4; i++) {
#pragma unroll
      for (int r = 0; r < 4; r++) {
        int row = hbase + wm + i * 16 + lq * 4 + r;
        H[(size_t)row * DFF + col] = (__bf16)gelu_f(acc[i][j][r] + bias);
      }
    }
  }
}

// ---------------- GEMM2: out[tok] = H @ W2[e] + b2[e] ----------------
__global__ __launch_bounds__(256, 2) void k_gemm2(
    const __bf16* __restrict__ H, const float* __restrict__ W2,
    const float* __restrict__ b2, const int* __restrict__ bucket,
    const int* __restrict__ po, float* __restrict__ out, int base_row)
{
  __shared__ __bf16 As[BM * LDA];
  __shared__ __bf16 Bs[BN * LDB];
  __shared__ int toks[BM];

  const int tid = threadIdx.x;
  const int total = po[NEXP];
  const int row0 = base_row + (int)blockIdx.x * BM;
  if (row0 >= total) return;
  const int nb0 = (int)blockIdx.y * BN;

  int e = 0;
#pragma unroll
  for (int k = 1; k < NEXP; k++) e = (row0 >= po[k]) ? k : e;
  const float* __restrict__ W = W2 + (size_t)e * DFF * DMODEL;

  if (tid < BM) toks[tid] = bucket[row0 + tid];
  __syncthreads();

  f32x4 acc[4][4];
#pragma unroll
  for (int i = 0; i < 4; i++)
#pragma unroll
    for (int j = 0; j < 4; j++) acc[i][j] = (f32x4)0.0f;

  const int wave = tid >> 6;
  const int lane = tid & 63;
  const int wm = (wave & 1) * 64;
  const int wn = (wave >> 1) * 64;
  const int lm = lane & 15;
  const int lq = lane >> 4;

  const int bn = tid & 127;
  const int bkh = (tid >> 7) * 16;
  const int hbase = (int)blockIdx.x * BM;

  for (int k0 = 0; k0 < DFF; k0 += BK) {
    // stage A from H (already bf16, contiguous)
#pragma unroll
    for (int i = 0; i < 2; i++) {
      int idx = tid + i * 256;
      int row = idx >> 2, kq = idx & 3;
      bf16x8 v = *(const bf16x8*)(H + (size_t)(hbase + row) * DFF + k0 + kq * 8);
      *(bf16x8*)&As[row * LDA + kq * 8] = v;
    }
    // stage B transposed from W2 fp32
    {
      const float* src = W + (size_t)(k0 + bkh) * DMODEL + nb0 + bn;
      bf16x8 b0, b1v;
#pragma unroll
      for (int kk = 0; kk < 8; kk++) b0[kk] = (__bf16)src[(size_t)kk * DMODEL];
#pragma unroll
      for (int kk = 0; kk < 8; kk++) b1v[kk] = (__bf16)src[(size_t)(kk + 8) * DMODEL];
      *(bf16x8*)&Bs[bn * LDB + bkh] = b0;
      *(bf16x8*)&Bs[bn * LDB + bkh + 8] = b1v;
    }
    __syncthreads();

    bf16x8 af[4], bfr[4];
#pragma unroll
    for (int i = 0; i < 4; i++)
      af[i] = *(const bf16x8*)&As[(wm + i * 16 + lm) * LDA + lq * 8];
#pragma unroll
    for (int j = 0; j < 4; j++)
      bfr[j] = *(const bf16x8*)&Bs[(wn + j * 16 + lm) * LDB + lq * 8];
#pragma unroll
    for (int i = 0; i < 4; i++)
#pragma unroll
      for (int j = 0; j < 4; j++)
        acc[i][j] = __builtin_amdgcn_mfma_f32_16x16x32_bf16(af[i], bfr[j], acc[i][j], 0, 0, 0);
    __syncthreads();
  }

  const float* __restrict__ b2e = b2 + e * DMODEL;
#pragma unroll
  for (int j = 0; j < 4; j++) {
    const int col = nb0 + wn + j * 16 + lm;
    const float bias = b2e[col];
#pragma unroll
    for (int i = 0; i < 4; i++) {
#pragma unroll
      for (int r = 0; r < 4; r++) {
        int lrow = wm + i * 16 + lq * 4 + r;
        int t = toks[lrow];
        if (t >= 0) out[(size_t)t * DMODEL + col] = acc[i][j][r] + bias;
      }
    }
  }
}

// ---------------- fallback (only if workspace is tiny): per-token GEMV ----------------
__global__ __launch_bounds__(256) void k_fallback(
    const float* __restrict__ X, const int* __restrict__ idx,
    const float* __restrict__ W1, const float* __restrict__ b1,
    const float* __restrict__ W2, const float* __restrict__ b2,
    float* __restrict__ out)
{
  __shared__ float xs[DMODEL];
  __shared__ float hs[DFF];
  const int t = blockIdx.x;
  const int e = idx[t];
  const int tid = threadIdx.x;
  const float* w1 = W1 + (size_t)e * DMODEL * DFF;
  const float* w2 = W2 + (size_t)e * DFF * DMODEL;
  for (int i = tid; i < DMODEL; i += 256) xs[i] = X[(size_t)t * DMODEL + i];
  __syncthreads();
  for (int f = tid; f < DFF; f += 256) {
    float a = 0.f;
    for (int d = 0; d < DMODEL; d++) a += xs[d] * w1[(size_t)d * DFF + f];
    hs[f] = gelu_f(a + b1[e * DFF + f]);
  }
  __syncthreads();
  for (int d = tid; d < DMODEL; d += 256) {
    float a = 0.f;
    for (int f = 0; f < DFF; f++) a += hs[f] * w2[(size_t)f * DMODEL + d];
    out[(size_t)t * DMODEL + d] = a + b2[e * DMODEL + d];
  }
}

extern "C" void kernel_launch(void* const* d_in, const int* in_sizes, int n_in,
                              void* d_out, int out_size, void* d_ws, size_t ws_size,
                              hipStream_t stream) {
  const float* X  = (const float*)d_in[0];
  const int*   EI = (const int*)d_in[1];
  const float* W1 = (const float*)d_in[2];
  const float* b1 = (const float*)d_in[3];
  const float* W2 = (const float*)d_in[4];
  const float* b2 = (const float*)d_in[5];
  float* out = (float*)d_out;

  char* ws = (char*)d_ws;
  int* counts  = (int*)(ws + 0);
  int* cursors = (int*)(ws + 32);
  int* po      = (int*)(ws + 64);
  int* bucket  = (int*)(ws + 512);
  const size_t H_OFF = 512 + (size_t)(T_TOK + NEXP * BM) * 4;  // 70144, 16B aligned
  __bf16* H = (__bf16*)(ws + H_OFF);

  const int Tpad = T_TOK + NEXP * BM;  // 17408 = 136 * BM

  size_t avail = (ws_size > H_OFF) ? ws_size - H_OFF : 0;
  long long crll = (long long)(avail / ((size_t)DFF * 2));
  int CR = (crll > Tpad) ? Tpad : (int)crll;
  CR -= CR % BM;

  if (CR < BM) {
    // workspace too small for grouped path
    k_fallback<<<T_TOK, 256, 0, stream>>>(X, EI, W1, b1, W2, b2, out);
    return;
  }

  k_init<<<(Tpad + 255) / 256, 256, 0, stream>>>(counts, cursors, bucket, Tpad);
  k_hist<<<(T_TOK + 255) / 256, 256, 0, stream>>>(EI, counts);
  k_scan<<<1, 64, 0, stream>>>(counts, po);
  k_scatter<<<(T_TOK + 255) / 256, 256, 0, stream>>>(EI, po, cursors, bucket);

  int nchunks = (Tpad + CR - 1) / CR;
  for (int c = 0; c < nchunks; c++) {
    int base = c * CR;
    int rows = Tpad - base; if (rows > CR) rows = CR;
    int mt = rows / BM;
    k_gemm1<<<dim3(mt, DFF / BN), 256, 0, stream>>>(X, W1, b1, bucket, po, H, base);
    k_gemm2<<<dim3(mt, DMODEL / BN), 256, 0, stream>>>(H, W2, b2, bucket, po, out, base);
  }
}

// Round 2
// 1056.496 us; speedup vs baseline: 1.2851x; 1.2851x over previous
//
#include <hip/hip_runtime.h>

#define T_TOK 16384
#define DMODEL 1024
#define DFF 4096
#define NEXP 8
#define BM 128
#define BN 128
#define BK 32
#define LDA 40   // fallback path: BK + 8 bf16 pad
#define LDB 40
#define TPAD (T_TOK + NEXP * BM)   // 17408

typedef __bf16 bf16x8 __attribute__((ext_vector_type(8)));
typedef float f32x4 __attribute__((ext_vector_type(4)));

// async global->LDS, 16B per lane; LDS dest = wave-uniform base + lane*16
#define GLOAD16(gp, lp) __builtin_amdgcn_global_load_lds( \
    (const __attribute__((address_space(1))) void*)(gp), \
    (__attribute__((address_space(3))) void*)(lp), 16, 0, 0)

__device__ __forceinline__ float gelu_f(float x) {
  // jax.nn.gelu approximate=True (tanh form); overflow-safe tanh via exp
  float u = 0.7978845608028654f * (x + 0.044715f * x * x * x);
  float e = __expf(2.0f * u);
  float th = 1.0f - 2.0f / (e + 1.0f);
  return 0.5f * x * (1.0f + th);
}

// ---------------- routing ----------------
__global__ void k_init(int* counts, int* cursors, int* bucket, int n) {
  int i = blockIdx.x * blockDim.x + threadIdx.x;
  if (i < n) bucket[i] = -1;
  if (i < NEXP) { counts[i] = 0; cursors[i] = 0; }
}

__global__ void k_hist(const int* __restrict__ idx, int* counts) {
  int t = blockIdx.x * blockDim.x + threadIdx.x;
  if (t < T_TOK) atomicAdd(&counts[idx[t]], 1);
}

__global__ void k_scan(const int* __restrict__ counts, int* po) {
  if (threadIdx.x == 0 && blockIdx.x == 0) {
    int acc = 0;
    for (int e = 0; e < NEXP; e++) {
      po[e] = acc;
      acc += ((counts[e] + BM - 1) / BM) * BM;
    }
    po[NEXP] = acc;
  }
}

__global__ void k_scatter(const int* __restrict__ idx, const int* __restrict__ po,
                          int* cursors, int* bucket) {
  int t = blockIdx.x * blockDim.x + threadIdx.x;
  if (t < T_TOK) {
    int e = idx[t];
    int p = atomicAdd(&cursors[e], 1);
    bucket[po[e] + p] = t;
  }
}

// ---------------- pre-passes (fast path) ----------------
// gather X rows into bucket order, fp32 -> bf16
__global__ __launch_bounds__(256) void k_gather(
    const float* __restrict__ X, const int* __restrict__ bucket,
    __bf16* __restrict__ Xg)
{
  const int r = blockIdx.x;
  const int t = bucket[r];
  const int c = threadIdx.x * 4;
  float4 v = {0.f, 0.f, 0.f, 0.f};
  if (t >= 0) v = *(const float4*)&X[(size_t)t * DMODEL + c];
  union { __bf16 h[4]; uint2 u; } cv;
  cv.h[0] = (__bf16)v.x; cv.h[1] = (__bf16)v.y;
  cv.h[2] = (__bf16)v.z; cv.h[3] = (__bf16)v.w;
  *(uint2*)&Xg[(size_t)r * DMODEL + c] = cv.u;
}

// W [e][K][N] fp32 -> Wt [e][N][K] bf16 (64x64 LDS tile transpose)
__global__ __launch_bounds__(256) void k_transpose(
    const float* __restrict__ W, __bf16* __restrict__ Wt, int K, int N)
{
  __shared__ float tile[64][65];
  const size_t msz = (size_t)K * N;
  const float* __restrict__ src = W + (size_t)blockIdx.z * msz;
  __bf16* __restrict__ dst = Wt + (size_t)blockIdx.z * msz;
  const int n0 = blockIdx.x * 64, k0 = blockIdx.y * 64;
  const int tc = threadIdx.x & 15, tr = threadIdx.x >> 4;
#pragma unroll
  for (int i = 0; i < 4; i++) {
    float4 v = *(const float4*)&src[(size_t)(k0 + tr + i * 16) * N + n0 + tc * 4];
    tile[tr + i * 16][tc * 4 + 0] = v.x;
    tile[tr + i * 16][tc * 4 + 1] = v.y;
    tile[tr + i * 16][tc * 4 + 2] = v.z;
    tile[tr + i * 16][tc * 4 + 3] = v.w;
  }
  __syncthreads();
#pragma unroll
  for (int i = 0; i < 4; i++) {
    const int n = tr + i * 16;
    union { __bf16 h[4]; uint2 u; } cv;
    cv.h[0] = (__bf16)tile[tc * 4 + 0][n];
    cv.h[1] = (__bf16)tile[tc * 4 + 1][n];
    cv.h[2] = (__bf16)tile[tc * 4 + 2][n];
    cv.h[3] = (__bf16)tile[tc * 4 + 3][n];
    *(uint2*)&dst[(size_t)(n0 + n) * K + k0 + tc * 4] = cv.u;
  }
}

// ---------------- fast GEMM1: H = gelu(Xg @ W1t^T + b1) ----------------
__global__ __launch_bounds__(256, 2) void k_gemm1b(
    const __bf16* __restrict__ Ag, const __bf16* __restrict__ Wt,
    const float* __restrict__ b1, const int* __restrict__ po,
    __bf16* __restrict__ H)
{
  __shared__ __align__(16) __bf16 As[BM * BK];
  __shared__ __align__(16) __bf16 Bs[BN * BK];
  const int tid = threadIdx.x;
  const int row0 = (int)blockIdx.x * BM;
  if (row0 >= po[NEXP]) return;
  const int nb0 = (int)blockIdx.y * BN;

  int e = 0;
#pragma unroll
  for (int k = 1; k < NEXP; k++) e = (row0 >= po[k]) ? k : e;
  const __bf16* __restrict__ B = Wt + (size_t)e * DFF * DMODEL;  // [4096][1024]

  f32x4 acc[4][4];
#pragma unroll
  for (int i = 0; i < 4; i++)
#pragma unroll
    for (int j = 0; j < 4; j++) acc[i][j] = (f32x4)0.0f;

  const int wave = tid >> 6;
  const int lane = tid & 63;
  const int wm = (wave & 1) * 64;
  const int wn = (wave >> 1) * 64;
  const int lm = lane & 15;
  const int lq = lane >> 4;

  // staging: wave w covers rows [w*32, w*32+32) in 2 calls of 16 rows
  const int sr = wave * 32 + (lane >> 2);
  const int skq = lane & 3;
  const __bf16* Aptr = Ag + (size_t)(row0 + sr) * DMODEL + skq * 8;
  const __bf16* Bptr = B + (size_t)(nb0 + sr) * DMODEL + skq * 8;
  __bf16* Al = &As[wave * 1024];
  __bf16* Bl = &Bs[wave * 1024];

  for (int k0 = 0; k0 < DMODEL; k0 += BK) {
    GLOAD16(Aptr + k0, Al);
    GLOAD16(Aptr + k0 + 16 * DMODEL, Al + 512);
    GLOAD16(Bptr + k0, Bl);
    GLOAD16(Bptr + k0 + 16 * DMODEL, Bl + 512);
    __syncthreads();

    bf16x8 af[4], bfr[4];
#pragma unroll
    for (int i = 0; i < 4; i++)
      af[i] = *(const bf16x8*)&As[(wm + i * 16 + lm) * BK + lq * 8];
#pragma unroll
    for (int j = 0; j < 4; j++)
      bfr[j] = *(const bf16x8*)&Bs[(wn + j * 16 + lm) * BK + lq * 8];
#pragma unroll
    for (int i = 0; i < 4; i++)
#pragma unroll
      for (int j = 0; j < 4; j++)
        acc[i][j] = __builtin_amdgcn_mfma_f32_16x16x32_bf16(af[i], bfr[j], acc[i][j], 0, 0, 0);
    __syncthreads();
  }

  const float* __restrict__ b1e = b1 + e * DFF;
#pragma unroll
  for (int j = 0; j < 4; j++) {
    const int col = nb0 + wn + j * 16 + lm;
    const float bias = b1e[col];
#pragma unroll
    for (int i = 0; i < 4; i++) {
#pragma unroll
      for (int r = 0; r < 4; r++) {
        int row = row0 + wm + i * 16 + lq * 4 + r;
        H[(size_t)row * DFF + col] = (__bf16)gelu_f(acc[i][j][r] + bias);
      }
    }
  }
}

// ---------------- fast GEMM2: out[tok] = H @ W2t^T + b2 ----------------
__global__ __launch_bounds__(256, 2) void k_gemm2b(
    const __bf16* __restrict__ H, const __bf16* __restrict__ Wt,
    const float* __restrict__ b2, const int* __restrict__ bucket,
    const int* __restrict__ po, float* __restrict__ out)
{
  __shared__ __align__(16) __bf16 As[BM * BK];
  __shared__ __align__(16) __bf16 Bs[BN * BK];
  __shared__ int toks[BM];
  const int tid = threadIdx.x;
  const int row0 = (int)blockIdx.x * BM;
  if (row0 >= po[NEXP]) return;
  const int nb0 = (int)blockIdx.y * BN;

  int e = 0;
#pragma unroll
  for (int k = 1; k < NEXP; k++) e = (row0 >= po[k]) ? k : e;
  const __bf16* __restrict__ B = Wt + (size_t)e * DMODEL * DFF;  // [1024][4096]

  if (tid < BM) toks[tid] = bucket[row0 + tid];

  f32x4 acc[4][4];
#pragma unroll
  for (int i = 0; i < 4; i++)
#pragma unroll
    for (int j = 0; j < 4; j++) acc[i][j] = (f32x4)0.0f;

  const int wave = tid >> 6;
  const int lane = tid & 63;
  const int wm = (wave & 1) * 64;
  const int wn = (wave >> 1) * 64;
  const int lm = lane & 15;
  const int lq = lane >> 4;

  const int sr = wave * 32 + (lane >> 2);
  const int skq = lane & 3;
  const __bf16* Aptr = H + (size_t)(row0 + sr) * DFF + skq * 8;
  const __bf16* Bptr = B + (size_t)(nb0 + sr) * DFF + skq * 8;
  __bf16* Al = &As[wave * 1024];
  __bf16* Bl = &Bs[wave * 1024];

  for (int k0 = 0; k0 < DFF; k0 += BK) {
    GLOAD16(Aptr + k0, Al);
    GLOAD16(Aptr + k0 + 16 * DFF, Al + 512);
    GLOAD16(Bptr + k0, Bl);
    GLOAD16(Bptr + k0 + 16 * DFF, Bl + 512);
    __syncthreads();

    bf16x8 af[4], bfr[4];
#pragma unroll
    for (int i = 0; i < 4; i++)
      af[i] = *(const bf16x8*)&As[(wm + i * 16 + lm) * BK + lq * 8];
#pragma unroll
    for (int j = 0; j < 4; j++)
      bfr[j] = *(const bf16x8*)&Bs[(wn + j * 16 + lm) * BK + lq * 8];
#pragma unroll
    for (int i = 0; i < 4; i++)
#pragma unroll
      for (int j = 0; j < 4; j++)
        acc[i][j] = __builtin_amdgcn_mfma_f32_16x16x32_bf16(af[i], bfr[j], acc[i][j], 0, 0, 0);
    __syncthreads();
  }

  const float* __restrict__ b2e = b2 + e * DMODEL;
#pragma unroll
  for (int j = 0; j < 4; j++) {
    const int col = nb0 + wn + j * 16 + lm;
    const float bias = b2e[col];
#pragma unroll
    for (int i = 0; i < 4; i++) {
#pragma unroll
      for (int r = 0; r < 4; r++) {
        int t = toks[wm + i * 16 + lq * 4 + r];
        if (t >= 0) out[(size_t)t * DMODEL + col] = acc[i][j][r] + bias;
      }
    }
  }
}

// ================= round-1 fallback path (inline-convert GEMMs) =================
__global__ __launch_bounds__(256, 2) void k_gemm1(
    const float* __restrict__ X, const float* __restrict__ W1,
    const float* __restrict__ b1, const int* __restrict__ bucket,
    const int* __restrict__ po, __bf16* __restrict__ H, int base_row)
{
  __shared__ __bf16 As[BM * LDA];
  __shared__ __bf16 Bs[BN * LDB];
  __shared__ int toks[BM];
  const int tid = threadIdx.x;
  const int total = po[NEXP];
  const int row0 = base_row + (int)blockIdx.x * BM;
  if (row0 >= total) return;
  const int nb0 = (int)blockIdx.y * BN;
  int e = 0;
#pragma unroll
  for (int k = 1; k < NEXP; k++) e = (row0 >= po[k]) ? k : e;
  const float* __restrict__ W = W1 + (size_t)e * DMODEL * DFF;
  if (tid < BM) toks[tid] = bucket[row0 + tid];
  __syncthreads();
  f32x4 acc[4][4];
#pragma unroll
  for (int i = 0; i < 4; i++)
#pragma unroll
    for (int j = 0; j < 4; j++) acc[i][j] = (f32x4)0.0f;
  const int wave = tid >> 6, lane = tid & 63;
  const int wm = (wave & 1) * 64, wn = (wave >> 1) * 64;
  const int lm = lane & 15, lq = lane >> 4;
  const int bn = tid & 127, bkh = (tid >> 7) * 16;
  for (int k0 = 0; k0 < DMODEL; k0 += BK) {
#pragma unroll
    for (int i = 0; i < 4; i++) {
      int idx = tid + i * 256;
      int row = idx >> 3, kq = idx & 7;
      int t = toks[row];
      float4 v = {0.f, 0.f, 0.f, 0.f};
      if (t >= 0) v = *(const float4*)(X + (size_t)t * DMODEL + k0 + kq * 4);
      union { __bf16 h[4]; uint2 u; } cv;
      cv.h[0] = (__bf16)v.x; cv.h[1] = (__bf16)v.y;
      cv.h[2] = (__bf16)v.z; cv.h[3] = (__bf16)v.w;
      *(uint2*)&As[row * LDA + kq * 4] = cv.u;
    }
    {
      const float* src = W + (size_t)(k0 + bkh) * DFF + nb0 + bn;
      bf16x8 b0, b1v;
#pragma unroll
      for (int kk = 0; kk < 8; kk++) b0[kk] = (__bf16)src[(size_t)kk * DFF];
#pragma unroll
      for (int kk = 0; kk < 8; kk++) b1v[kk] = (__bf16)src[(size_t)(kk + 8) * DFF];
      *(bf16x8*)&Bs[bn * LDB + bkh] = b0;
      *(bf16x8*)&Bs[bn * LDB + bkh + 8] = b1v;
    }
    __syncthreads();
    bf16x8 af[4], bfr[4];
#pragma unroll
    for (int i = 0; i < 4; i++)
      af[i] = *(const bf16x8*)&As[(wm + i * 16 + lm) * LDA + lq * 8];
#pragma unroll
    for (int j = 0; j < 4; j++)
      bfr[j] = *(const bf16x8*)&Bs[(wn + j * 16 + lm) * LDB + lq * 8];
#pragma unroll
    for (int i = 0; i < 4; i++)
#pragma unroll
      for (int j = 0; j < 4; j++)
        acc[i][j] = __builtin_amdgcn_mfma_f32_16x16x32_bf16(af[i], bfr[j], acc[i][j], 0, 0, 0);
    __syncthreads();
  }
  const float* __restrict__ b1e = b1 + e * DFF;
  const int hbase = (int)blockIdx.x * BM;
#pragma unroll
  for (int j = 0; j < 4; j++) {
    const int col = nb0 + wn + j * 16 + lm;
    const float bias = b1e[col];
#pragma unroll
    for (int i = 0; i < 4; i++)
#pragma unroll
      for (int r = 0; r < 4; r++) {
        int row = hbase + wm + i * 16 + lq * 4 + r;
        H[(size_t)row * DFF + col] = (__bf16)gelu_f(acc[i][j][r] + bias);
      }
  }
}

__global__ __launch_bounds__(256, 2) void k_gemm2(
    const __bf16* __restrict__ H, const float* __restrict__ W2,
    const float* __restrict__ b2, const int* __restrict__ bucket,
    const int* __restrict__ po, float* __restrict__ out, int base_row)
{
  __shared__ __bf16 As[BM * LDA];
  __shared__ __bf16 Bs[BN * LDB];
  __shared__ int toks[BM];
  const int tid = threadIdx.x;
  const int total = po[NEXP];
  const int row0 = base_row + (int)blockIdx.x * BM;
  if (row0 >= total) return;
  const int nb0 = (int)blockIdx.y * BN;
  int e = 0;
#pragma unroll
  for (int k = 1; k < NEXP; k++) e = (row0 >= po[k]) ? k : e;
  const float* __restrict__ W = W2 + (size_t)e * DFF * DMODEL;
  if (tid < BM) toks[tid] = bucket[row0 + tid];
  __syncthreads();
  f32x4 acc[4][4];
#pragma unroll
  for (int i = 0; i < 4; i++)
#pragma unroll
    for (int j = 0; j < 4; j++) acc[i][j] = (f32x4)0.0f;
  const int wave = tid >> 6, lane = tid & 63;
  const int wm = (wave & 1) * 64, wn = (wave >> 1) * 64;
  const int lm = lane & 15, lq = lane >> 4;
  const int bn = tid & 127, bkh = (tid >> 7) * 16;
  const int hbase = (int)blockIdx.x * BM;
  for (int k0 = 0; k0 < DFF; k0 += BK) {
#pragma unroll
    for (int i = 0; i < 2; i++) {
      int idx = tid + i * 256;
      int row = idx >> 2, kq = idx & 3;
      bf16x8 v = *(const bf16x8*)(H + (size_t)(hbase + row) * DFF + k0 + kq * 8);
      *(bf16x8*)&As[row * LDA + kq * 8] = v;
    }
    {
      const float* src = W + (size_t)(k0 + bkh) * DMODEL + nb0 + bn;
      bf16x8 b0, b1v;
#pragma unroll
      for (int kk = 0; kk < 8; kk++) b0[kk] = (__bf16)src[(size_t)kk * DMODEL];
#pragma unroll
      for (int kk = 0; kk < 8; kk++) b1v[kk] = (__bf16)src[(size_t)(kk + 8) * DMODEL];
      *(bf16x8*)&Bs[bn * LDB + bkh] = b0;
      *(bf16x8*)&Bs[bn * LDB + bkh + 8] = b1v;
    }
    __syncthreads();
    bf16x8 af[4], bfr[4];
#pragma unroll
    for (int i = 0; i < 4; i++)
      af[i] = *(const bf16x8*)&As[(wm + i * 16 + lm) * LDA + lq * 8];
#pragma unroll
    for (int j = 0; j < 4; j++)
      bfr[j] = *(const bf16x8*)&Bs[(wn + j * 16 + lm) * LDB + lq * 8];
#pragma unroll
    for (int i = 0; i < 4; i++)
#pragma unroll
      for (int j = 0; j < 4; j++)
        acc[i][j] = __builtin_amdgcn_mfma_f32_16x16x32_bf16(af[i], bfr[j], acc[i][j], 0, 0, 0);
    __syncthreads();
  }
  const float* __restrict__ b2e = b2 + e * DMODEL;
#pragma unroll
  for (int j = 0; j < 4; j++) {
    const int col = nb0 + wn + j * 16 + lm;
    const float bias = b2e[col];
#pragma unroll
    for (int i = 0; i < 4; i++)
#pragma unroll
      for (int r = 0; r < 4; r++) {
        int t = toks[wm + i * 16 + lq * 4 + r];
        if (t >= 0) out[(size_t)t * DMODEL + col] = acc[i][j][r] + bias;
      }
  }
}

__global__ __launch_bounds__(256) void k_fallback(
    const float* __restrict__ X, const int* __restrict__ idx,
    const float* __restrict__ W1, const float* __restrict__ b1,
    const float* __restrict__ W2, const float* __restrict__ b2,
    float* __restrict__ out)
{
  __shared__ float xs[DMODEL];
  __shared__ float hs[DFF];
  const int t = blockIdx.x;
  const int e = idx[t];
  const int tid = threadIdx.x;
  const float* w1 = W1 + (size_t)e * DMODEL * DFF;
  const float* w2 = W2 + (size_t)e * DFF * DMODEL;
  for (int i = tid; i < DMODEL; i += 256) xs[i] = X[(size_t)t * DMODEL + i];
  __syncthreads();
  for (int f = tid; f < DFF; f += 256) {
    float a = 0.f;
    for (int d = 0; d < DMODEL; d++) a += xs[d] * w1[(size_t)d * DFF + f];
    hs[f] = gelu_f(a + b1[e * DFF + f]);
  }
  __syncthreads();
  for (int d = tid; d < DMODEL; d += 256) {
    float a = 0.f;
    for (int f = 0; f < DFF; f++) a += hs[f] * w2[(size_t)f * DMODEL + d];
    out[(size_t)t * DMODEL + d] = a + b2[e * DMODEL + d];
  }
}

extern "C" void kernel_launch(void* const* d_in, const int* in_sizes, int n_in,
                              void* d_out, int out_size, void* d_ws, size_t ws_size,
                              hipStream_t stream) {
  const float* X  = (const float*)d_in[0];
  const int*   EI = (const int*)d_in[1];
  const float* W1 = (const float*)d_in[2];
  const float* b1 = (const float*)d_in[3];
  const float* W2 = (const float*)d_in[4];
  const float* b2 = (const float*)d_in[5];
  float* out = (float*)d_out;

  char* ws = (char*)d_ws;
  int* counts  = (int*)(ws + 0);
  int* cursors = (int*)(ws + 32);
  int* po      = (int*)(ws + 64);
  int* bucket  = (int*)(ws + 512);
  const int Tpad = TPAD;  // 17408

  // fast-path workspace layout
  const size_t XG_OFF = 70144;                                   // 256-aligned
  const size_t XG_SZ  = (size_t)Tpad * DMODEL * 2;               // 35,651,584
  const size_t WT_OFF = XG_OFF + XG_SZ;
  const size_t WT_SZ  = (size_t)NEXP * DMODEL * DFF * 2;         // 67,108,864
  const size_t HF_OFF = WT_OFF + WT_SZ;
  const size_t H_SZ   = (size_t)Tpad * DFF * 2;                  // 142,606,336
  const size_t NEED   = HF_OFF + H_SZ;                           // ~245.4 MB

  if (ws_size >= NEED) {
    __bf16* Xg = (__bf16*)(ws + XG_OFF);
    __bf16* Wt = (__bf16*)(ws + WT_OFF);
    __bf16* H  = (__bf16*)(ws + HF_OFF);

    k_init<<<(Tpad + 255) / 256, 256, 0, stream>>>(counts, cursors, bucket, Tpad);
    k_hist<<<(T_TOK + 255) / 256, 256, 0, stream>>>(EI, counts);
    k_scan<<<1, 64, 0, stream>>>(counts, po);
    k_scatter<<<(T_TOK + 255) / 256, 256, 0, stream>>>(EI, po, cursors, bucket);
    k_gather<<<Tpad, 256, 0, stream>>>(X, bucket, Xg);
    // W1 [8][1024][4096] -> Wt [8][4096][1024]
    k_transpose<<<dim3(DFF / 64, DMODEL / 64, NEXP), 256, 0, stream>>>(W1, Wt, DMODEL, DFF);
    k_gemm1b<<<dim3(Tpad / BM, DFF / BN), 256, 0, stream>>>(Xg, Wt, b1, po, H);
    // W2 [8][4096][1024] -> Wt [8][1024][4096] (reuse buffer)
    k_transpose<<<dim3(DMODEL / 64, DFF / 64, NEXP), 256, 0, stream>>>(W2, Wt, DFF, DMODEL);
    k_gemm2b<<<dim3(Tpad / BM, DMODEL / BN), 256, 0, stream>>>(H, Wt, b2, bucket, po, out);
    return;
  }

  // ---- round-1 fallback path ----
  const size_t H_OFF = 512 + (size_t)Tpad * 4;  // 70144
  __bf16* H = (__bf16*)(ws + H_OFF);
  size_t avail = (ws_size > H_OFF) ? ws_size - H_OFF : 0;
  long long crll = (long long)(avail / ((size_t)DFF * 2));
  int CR = (crll > Tpad) ? Tpad : (int)crll;
  CR -= CR % BM;
  if (CR < BM) {
    k_fallback<<<T_TOK, 256, 0, stream>>>(X, EI, W1, b1, W2, b2, out);
    return;
  }
  k_init<<<(Tpad + 255) / 256, 256, 0, stream>>>(counts, cursors, bucket, Tpad);
  k_hist<<<(T_TOK + 255) / 256, 256, 0, stream>>>(EI, counts);
  k_scan<<<1, 64, 0, stream>>>(counts, po);
  k_scatter<<<(T_TOK + 255) / 256, 256, 0, stream>>>(EI, po, cursors, bucket);
  int nchunks = (Tpad + CR - 1) / CR;
  for (int c = 0; c < nchunks; c++) {
    int base = c * CR;
    int rows = Tpad - base; if (rows > CR) rows = CR;
    int mt = rows / BM;
    k_gemm1<<<dim3(mt, DFF / BN), 256, 0, stream>>>(X, W1, b1, bucket, po, H, base);
    k_gemm2<<<dim3(mt, DMODEL / BN), 256, 0, stream>>>(H, W2, b2, bucket, po, out, base);
  }
}

// Round 3
// 965.568 us; speedup vs baseline: 1.4061x; 1.0942x over previous
//
#include <hip/hip_runtime.h>

#define T_TOK 16384
#define DMODEL 1024
#define DFF 4096
#define NEXP 8
#define BM 128
#define BN 128
#define BK 32
#define LDA 40   // fallback path: BK + 8 bf16 pad
#define LDB 40
#define TPAD (T_TOK + NEXP * BM)   // 17408

typedef __bf16 bf16x8 __attribute__((ext_vector_type(8)));
typedef float f32x4 __attribute__((ext_vector_type(4)));

// async global->LDS, 16B per lane; LDS dest = wave-uniform base + lane*16
#define GLOAD16(gp, lp) __builtin_amdgcn_global_load_lds( \
    (const __attribute__((address_space(1))) void*)(gp), \
    (__attribute__((address_space(3))) void*)(lp), 16, 0, 0)

__device__ __forceinline__ float gelu_f(float x) {
  float u = 0.7978845608028654f * (x + 0.044715f * x * x * x);
  float e = __expf(2.0f * u);
  float th = 1.0f - 2.0f / (e + 1.0f);
  return 0.5f * x * (1.0f + th);
}

// ---------------- routing ----------------
__global__ void k_init(int* counts, int* cursors, int* bucket, int n) {
  int i = blockIdx.x * blockDim.x + threadIdx.x;
  if (i < n) bucket[i] = -1;
  if (i < NEXP) { counts[i] = 0; cursors[i] = 0; }
}

__global__ void k_hist(const int* __restrict__ idx, int* counts) {
  int t = blockIdx.x * blockDim.x + threadIdx.x;
  if (t < T_TOK) atomicAdd(&counts[idx[t]], 1);
}

__global__ void k_scan(const int* __restrict__ counts, int* po) {
  if (threadIdx.x == 0 && blockIdx.x == 0) {
    int acc = 0;
    for (int e = 0; e < NEXP; e++) {
      po[e] = acc;
      acc += ((counts[e] + BM - 1) / BM) * BM;
    }
    po[NEXP] = acc;
  }
}

__global__ void k_scatter(const int* __restrict__ idx, const int* __restrict__ po,
                          int* cursors, int* bucket) {
  int t = blockIdx.x * blockDim.x + threadIdx.x;
  if (t < T_TOK) {
    int e = idx[t];
    int p = atomicAdd(&cursors[e], 1);
    bucket[po[e] + p] = t;
  }
}

// ---------------- pre-passes (fast path) ----------------
__global__ __launch_bounds__(256) void k_gather(
    const float* __restrict__ X, const int* __restrict__ bucket,
    __bf16* __restrict__ Xg)
{
  const int r = blockIdx.x;
  const int t = bucket[r];
  const int c = threadIdx.x * 4;
  float4 v = {0.f, 0.f, 0.f, 0.f};
  if (t >= 0) v = *(const float4*)&X[(size_t)t * DMODEL + c];
  union { __bf16 h[4]; uint2 u; } cv;
  cv.h[0] = (__bf16)v.x; cv.h[1] = (__bf16)v.y;
  cv.h[2] = (__bf16)v.z; cv.h[3] = (__bf16)v.w;
  *(uint2*)&Xg[(size_t)r * DMODEL + c] = cv.u;
}

// W [e][K][N] fp32 -> Wt [e][N][K] bf16 (64x64 LDS tile transpose)
__global__ __launch_bounds__(256) void k_transpose(
    const float* __restrict__ W, __bf16* __restrict__ Wt, int K, int N)
{
  __shared__ float tile[64][65];
  const size_t msz = (size_t)K * N;
  const float* __restrict__ src = W + (size_t)blockIdx.z * msz;
  __bf16* __restrict__ dst = Wt + (size_t)blockIdx.z * msz;
  const int n0 = blockIdx.x * 64, k0 = blockIdx.y * 64;
  const int tc = threadIdx.x & 15, tr = threadIdx.x >> 4;
#pragma unroll
  for (int i = 0; i < 4; i++) {
    float4 v = *(const float4*)&src[(size_t)(k0 + tr + i * 16) * N + n0 + tc * 4];
    tile[tr + i * 16][tc * 4 + 0] = v.x;
    tile[tr + i * 16][tc * 4 + 1] = v.y;
    tile[tr + i * 16][tc * 4 + 2] = v.z;
    tile[tr + i * 16][tc * 4 + 3] = v.w;
  }
  __syncthreads();
#pragma unroll
  for (int i = 0; i < 4; i++) {
    const int n = tr + i * 16;
    union { __bf16 h[4]; uint2 u; } cv;
    cv.h[0] = (__bf16)tile[tc * 4 + 0][n];
    cv.h[1] = (__bf16)tile[tc * 4 + 1][n];
    cv.h[2] = (__bf16)tile[tc * 4 + 2][n];
    cv.h[3] = (__bf16)tile[tc * 4 + 3][n];
    *(uint2*)&dst[(size_t)(n0 + n) * K + k0 + tc * 4] = cv.u;
  }
}

// ---------------- fast GEMM1: H = gelu(Xg @ W1t^T + b1) ----------------
// 1D grid, XCD-aware swizzle: xcd = bid&7 sweeps all 32 col-tiles of one
// row-strip consecutively (A strip stays in that XCD's L2; W streams via L3).
__global__ __launch_bounds__(256, 2) void k_gemm1b(
    const __bf16* __restrict__ Ag, const __bf16* __restrict__ Wt,
    const float* __restrict__ b1, const int* __restrict__ po,
    __bf16* __restrict__ H)
{
  __shared__ __align__(16) __bf16 As[BM * BK];
  __shared__ __align__(16) __bf16 Bs[BN * BK];
  const int tid = threadIdx.x;
  const int b = (int)blockIdx.x;
  const int slot = b >> 3;
  const int row_t = (b & 7) + ((slot >> 5) << 3);  // NCT=32
  const int col_t = slot & 31;
  const int row0 = row_t * BM;
  if (row0 >= po[NEXP]) return;
  const int nb0 = col_t * BN;

  int e = 0;
#pragma unroll
  for (int k = 1; k < NEXP; k++) e = (row0 >= po[k]) ? k : e;
  const __bf16* __restrict__ B = Wt + (size_t)e * DFF * DMODEL;  // [4096][1024]

  f32x4 acc[4][4];
#pragma unroll
  for (int i = 0; i < 4; i++)
#pragma unroll
    for (int j = 0; j < 4; j++) acc[i][j] = (f32x4)0.0f;

  const int wave = tid >> 6;
  const int lane = tid & 63;
  const int wm = (wave & 1) * 64;
  const int wn = (wave >> 1) * 64;
  const int lm = lane & 15;
  const int lq = lane >> 4;

  // staging with kquad XOR swizzle: lane l -> row l>>2, loads global kquad
  // g = (l&3) ^ ((l>>3)&3) into LDS slot (l&3). Bijective per 16-row batch.
  const int sr = wave * 32 + (lane >> 2);
  const int g  = (lane & 3) ^ ((lane >> 3) & 3);
  const __bf16* Aptr = Ag + (size_t)(row0 + sr) * DMODEL + g * 8;
  const __bf16* Bptr = B + (size_t)(nb0 + sr) * DMODEL + g * 8;
  __bf16* Al = &As[wave * 1024];
  __bf16* Bl = &Bs[wave * 1024];

  // fragment-read slot: global kquad lq of row r lives at slot lq ^ ((r>>1)&3);
  // (r>>1)&3 == (lm>>1)&3 for all our rows (offsets are multiples of 16).
  const int sA = (lm >> 1) & 3;

  for (int k0 = 0; k0 < DMODEL; k0 += BK) {
    GLOAD16(Aptr + k0, Al);
    GLOAD16(Aptr + k0 + 16 * DMODEL, Al + 512);
    GLOAD16(Bptr + k0, Bl);
    GLOAD16(Bptr + k0 + 16 * DMODEL, Bl + 512);
    __syncthreads();

    bf16x8 af[4], bfr[4];
#pragma unroll
    for (int i = 0; i < 4; i++)
      af[i] = *(const bf16x8*)&As[(wm + i * 16 + lm) * BK + (lq ^ sA) * 8];
#pragma unroll
    for (int j = 0; j < 4; j++)
      bfr[j] = *(const bf16x8*)&Bs[(wn + j * 16 + lm) * BK + (lq ^ sA) * 8];
#pragma unroll
    for (int i = 0; i < 4; i++)
#pragma unroll
      for (int j = 0; j < 4; j++)
        acc[i][j] = __builtin_amdgcn_mfma_f32_16x16x32_bf16(af[i], bfr[j], acc[i][j], 0, 0, 0);
    __syncthreads();
  }

  const float* __restrict__ b1e = b1 + e * DFF;
#pragma unroll
  for (int j = 0; j < 4; j++) {
    const int col = nb0 + wn + j * 16 + lm;
    const float bias = b1e[col];
#pragma unroll
    for (int i = 0; i < 4; i++) {
#pragma unroll
      for (int r = 0; r < 4; r++) {
        int row = row0 + wm + i * 16 + lq * 4 + r;
        H[(size_t)row * DFF + col] = (__bf16)gelu_f(acc[i][j][r] + bias);
      }
    }
  }
}

// ---------------- fast GEMM2: out[tok] = H @ W2t^T + b2 ----------------
__global__ __launch_bounds__(256, 2) void k_gemm2b(
    const __bf16* __restrict__ H, const __bf16* __restrict__ Wt,
    const float* __restrict__ b2, const int* __restrict__ bucket,
    const int* __restrict__ po, float* __restrict__ out)
{
  __shared__ __align__(16) __bf16 As[BM * BK];
  __shared__ __align__(16) __bf16 Bs[BN * BK];
  __shared__ int toks[BM];
  const int tid = threadIdx.x;
  const int b = (int)blockIdx.x;
  const int slot = b >> 3;
  const int row_t = (b & 7) + ((slot >> 3) << 3);  // NCT=8
  const int col_t = slot & 7;
  const int row0 = row_t * BM;
  if (row0 >= po[NEXP]) return;
  const int nb0 = col_t * BN;

  int e = 0;
#pragma unroll
  for (int k = 1; k < NEXP; k++) e = (row0 >= po[k]) ? k : e;
  const __bf16* __restrict__ B = Wt + (size_t)e * DMODEL * DFF;  // [1024][4096]

  if (tid < BM) toks[tid] = bucket[row0 + tid];

  f32x4 acc[4][4];
#pragma unroll
  for (int i = 0; i < 4; i++)
#pragma unroll
    for (int j = 0; j < 4; j++) acc[i][j] = (f32x4)0.0f;

  const int wave = tid >> 6;
  const int lane = tid & 63;
  const int wm = (wave & 1) * 64;
  const int wn = (wave >> 1) * 64;
  const int lm = lane & 15;
  const int lq = lane >> 4;

  const int sr = wave * 32 + (lane >> 2);
  const int g  = (lane & 3) ^ ((lane >> 3) & 3);
  const __bf16* Aptr = H + (size_t)(row0 + sr) * DFF + g * 8;
  const __bf16* Bptr = B + (size_t)(nb0 + sr) * DFF + g * 8;
  __bf16* Al = &As[wave * 1024];
  __bf16* Bl = &Bs[wave * 1024];
  const int sA = (lm >> 1) & 3;

  for (int k0 = 0; k0 < DFF; k0 += BK) {
    GLOAD16(Aptr + k0, Al);
    GLOAD16(Aptr + k0 + 16 * DFF, Al + 512);
    GLOAD16(Bptr + k0, Bl);
    GLOAD16(Bptr + k0 + 16 * DFF, Bl + 512);
    __syncthreads();

    bf16x8 af[4], bfr[4];
#pragma unroll
    for (int i = 0; i < 4; i++)
      af[i] = *(const bf16x8*)&As[(wm + i * 16 + lm) * BK + (lq ^ sA) * 8];
#pragma unroll
    for (int j = 0; j < 4; j++)
      bfr[j] = *(const bf16x8*)&Bs[(wn + j * 16 + lm) * BK + (lq ^ sA) * 8];
#pragma unroll
    for (int i = 0; i < 4; i++)
#pragma unroll
      for (int j = 0; j < 4; j++)
        acc[i][j] = __builtin_amdgcn_mfma_f32_16x16x32_bf16(af[i], bfr[j], acc[i][j], 0, 0, 0);
    __syncthreads();
  }

  const float* __restrict__ b2e = b2 + e * DMODEL;
#pragma unroll
  for (int j = 0; j < 4; j++) {
    const int col = nb0 + wn + j * 16 + lm;
    const float bias = b2e[col];
#pragma unroll
    for (int i = 0; i < 4; i++) {
#pragma unroll
      for (int r = 0; r < 4; r++) {
        int t = toks[wm + i * 16 + lq * 4 + r];
        if (t >= 0) out[(size_t)t * DMODEL + col] = acc[i][j][r] + bias;
      }
    }
  }
}

// ================= round-1 fallback path (inline-convert GEMMs) =================
__global__ __launch_bounds__(256, 2) void k_gemm1(
    const float* __restrict__ X, const float* __restrict__ W1,
    const float* __restrict__ b1, const int* __restrict__ bucket,
    const int* __restrict__ po, __bf16* __restrict__ H, int base_row)
{
  __shared__ __bf16 As[BM * LDA];
  __shared__ __bf16 Bs[BN * LDB];
  __shared__ int toks[BM];
  const int tid = threadIdx.x;
  const int total = po[NEXP];
  const int row0 = base_row + (int)blockIdx.x * BM;
  if (row0 >= total) return;
  const int nb0 = (int)blockIdx.y * BN;
  int e = 0;
#pragma unroll
  for (int k = 1; k < NEXP; k++) e = (row0 >= po[k]) ? k : e;
  const float* __restrict__ W = W1 + (size_t)e * DMODEL * DFF;
  if (tid < BM) toks[tid] = bucket[row0 + tid];
  __syncthreads();
  f32x4 acc[4][4];
#pragma unroll
  for (int i = 0; i < 4; i++)
#pragma unroll
    for (int j = 0; j < 4; j++) acc[i][j] = (f32x4)0.0f;
  const int wave = tid >> 6, lane = tid & 63;
  const int wm = (wave & 1) * 64, wn = (wave >> 1) * 64;
  const int lm = lane & 15, lq = lane >> 4;
  const int bn = tid & 127, bkh = (tid >> 7) * 16;
  for (int k0 = 0; k0 < DMODEL; k0 += BK) {
#pragma unroll
    for (int i = 0; i < 4; i++) {
      int idx = tid + i * 256;
      int row = idx >> 3, kq = idx & 7;
      int t = toks[row];
      float4 v = {0.f, 0.f, 0.f, 0.f};
      if (t >= 0) v = *(const float4*)(X + (size_t)t * DMODEL + k0 + kq * 4);
      union { __bf16 h[4]; uint2 u; } cv;
      cv.h[0] = (__bf16)v.x; cv.h[1] = (__bf16)v.y;
      cv.h[2] = (__bf16)v.z; cv.h[3] = (__bf16)v.w;
      *(uint2*)&As[row * LDA + kq * 4] = cv.u;
    }
    {
      const float* src = W + (size_t)(k0 + bkh) * DFF + nb0 + bn;
      bf16x8 b0, b1v;
#pragma unroll
      for (int kk = 0; kk < 8; kk++) b0[kk] = (__bf16)src[(size_t)kk * DFF];
#pragma unroll
      for (int kk = 0; kk < 8; kk++) b1v[kk] = (__bf16)src[(size_t)(kk + 8) * DFF];
      *(bf16x8*)&Bs[bn * LDB + bkh] = b0;
      *(bf16x8*)&Bs[bn * LDB + bkh + 8] = b1v;
    }
    __syncthreads();
    bf16x8 af[4], bfr[4];
#pragma unroll
    for (int i = 0; i < 4; i++)
      af[i] = *(const bf16x8*)&As[(wm + i * 16 + lm) * LDA + lq * 8];
#pragma unroll
    for (int j = 0; j < 4; j++)
      bfr[j] = *(const bf16x8*)&Bs[(wn + j * 16 + lm) * LDB + lq * 8];
#pragma unroll
    for (int i = 0; i < 4; i++)
#pragma unroll
      for (int j = 0; j < 4; j++)
        acc[i][j] = __builtin_amdgcn_mfma_f32_16x16x32_bf16(af[i], bfr[j], acc[i][j], 0, 0, 0);
    __syncthreads();
  }
  const float* __restrict__ b1e = b1 + e * DFF;
  const int hbase = (int)blockIdx.x * BM;
#pragma unroll
  for (int j = 0; j < 4; j++) {
    const int col = nb0 + wn + j * 16 + lm;
    const float bias = b1e[col];
#pragma unroll
    for (int i = 0; i < 4; i++)
#pragma unroll
      for (int r = 0; r < 4; r++) {
        int row = hbase + wm + i * 16 + lq * 4 + r;
        H[(size_t)row * DFF + col] = (__bf16)gelu_f(acc[i][j][r] + bias);
      }
  }
}

__global__ __launch_bounds__(256, 2) void k_gemm2(
    const __bf16* __restrict__ H, const float* __restrict__ W2,
    const float* __restrict__ b2, const int* __restrict__ bucket,
    const int* __restrict__ po, float* __restrict__ out, int base_row)
{
  __shared__ __bf16 As[BM * LDA];
  __shared__ __bf16 Bs[BN * LDB];
  __shared__ int toks[BM];
  const int tid = threadIdx.x;
  const int total = po[NEXP];
  const int row0 = base_row + (int)blockIdx.x * BM;
  if (row0 >= total) return;
  const int nb0 = (int)blockIdx.y * BN;
  int e = 0;
#pragma unroll
  for (int k = 1; k < NEXP; k++) e = (row0 >= po[k]) ? k : e;
  const float* __restrict__ W = W2 + (size_t)e * DFF * DMODEL;
  if (tid < BM) toks[tid] = bucket[row0 + tid];
  __syncthreads();
  f32x4 acc[4][4];
#pragma unroll
  for (int i = 0; i < 4; i++)
#pragma unroll
    for (int j = 0; j < 4; j++) acc[i][j] = (f32x4)0.0f;
  const int wave = tid >> 6, lane = tid & 63;
  const int wm = (wave & 1) * 64, wn = (wave >> 1) * 64;
  const int lm = lane & 15, lq = lane >> 4;
  const int bn = tid & 127, bkh = (tid >> 7) * 16;
  const int hbase = (int)blockIdx.x * BM;
  for (int k0 = 0; k0 < DFF; k0 += BK) {
#pragma unroll
    for (int i = 0; i < 2; i++) {
      int idx = tid + i * 256;
      int row = idx >> 2, kq = idx & 3;
      bf16x8 v = *(const bf16x8*)(H + (size_t)(hbase + row) * DFF + k0 + kq * 8);
      *(bf16x8*)&As[row * LDA + kq * 8] = v;
    }
    {
      const float* src = W + (size_t)(k0 + bkh) * DMODEL + nb0 + bn;
      bf16x8 b0, b1v;
#pragma unroll
      for (int kk = 0; kk < 8; kk++) b0[kk] = (__bf16)src[(size_t)kk * DMODEL];
#pragma unroll
      for (int kk = 0; kk < 8; kk++) b1v[kk] = (__bf16)src[(size_t)(kk + 8) * DMODEL];
      *(bf16x8*)&Bs[bn * LDB + bkh] = b0;
      *(bf16x8*)&Bs[bn * LDB + bkh + 8] = b1v;
    }
    __syncthreads();
    bf16x8 af[4], bfr[4];
#pragma unroll
    for (int i = 0; i < 4; i++)
      af[i] = *(const bf16x8*)&As[(wm + i * 16 + lm) * LDA + lq * 8];
#pragma unroll
    for (int j = 0; j < 4; j++)
      bfr[j] = *(const bf16x8*)&Bs[(wn + j * 16 + lm) * LDB + lq * 8];
#pragma unroll
    for (int i = 0; i < 4; i++)
#pragma unroll
      for (int j = 0; j < 4; j++)
        acc[i][j] = __builtin_amdgcn_mfma_f32_16x16x32_bf16(af[i], bfr[j], acc[i][j], 0, 0, 0);
    __syncthreads();
  }
  const float* __restrict__ b2e = b2 + e * DMODEL;
#pragma unroll
  for (int j = 0; j < 4; j++) {
    const int col = nb0 + wn + j * 16 + lm;
    const float bias = b2e[col];
#pragma unroll
    for (int i = 0; i < 4; i++)
#pragma unroll
      for (int r = 0; r < 4; r++) {
        int t = toks[wm + i * 16 + lq * 4 + r];
        if (t >= 0) out[(size_t)t * DMODEL + col] = acc[i][j][r] + bias;
      }
  }
}

__global__ __launch_bounds__(256) void k_fallback(
    const float* __restrict__ X, const int* __restrict__ idx,
    const float* __restrict__ W1, const float* __restrict__ b1,
    const float* __restrict__ W2, const float* __restrict__ b2,
    float* __restrict__ out)
{
  __shared__ float xs[DMODEL];
  __shared__ float hs[DFF];
  const int t = blockIdx.x;
  const int e = idx[t];
  const int tid = threadIdx.x;
  const float* w1 = W1 + (size_t)e * DMODEL * DFF;
  const float* w2 = W2 + (size_t)e * DFF * DMODEL;
  for (int i = tid; i < DMODEL; i += 256) xs[i] = X[(size_t)t * DMODEL + i];
  __syncthreads();
  for (int f = tid; f < DFF; f += 256) {
    float a = 0.f;
    for (int d = 0; d < DMODEL; d++) a += xs[d] * w1[(size_t)d * DFF + f];
    hs[f] = gelu_f(a + b1[e * DFF + f]);
  }
  __syncthreads();
  for (int d = tid; d < DMODEL; d += 256) {
    float a = 0.f;
    for (int f = 0; f < DFF; f++) a += hs[f] * w2[(size_t)f * DMODEL + d];
    out[(size_t)t * DMODEL + d] = a + b2[e * DMODEL + d];
  }
}

extern "C" void kernel_launch(void* const* d_in, const int* in_sizes, int n_in,
                              void* d_out, int out_size, void* d_ws, size_t ws_size,
                              hipStream_t stream) {
  const float* X  = (const float*)d_in[0];
  const int*   EI = (const int*)d_in[1];
  const float* W1 = (const float*)d_in[2];
  const float* b1 = (const float*)d_in[3];
  const float* W2 = (const float*)d_in[4];
  const float* b2 = (const float*)d_in[5];
  float* out = (float*)d_out;

  char* ws = (char*)d_ws;
  int* counts  = (int*)(ws + 0);
  int* cursors = (int*)(ws + 32);
  int* po      = (int*)(ws + 64);
  int* bucket  = (int*)(ws + 512);
  const int Tpad = TPAD;  // 17408

  const size_t XG_OFF = 70144;
  const size_t XG_SZ  = (size_t)Tpad * DMODEL * 2;
  const size_t WT_OFF = XG_OFF + XG_SZ;
  const size_t WT_SZ  = (size_t)NEXP * DMODEL * DFF * 2;
  const size_t HF_OFF = WT_OFF + WT_SZ;
  const size_t H_SZ   = (size_t)Tpad * DFF * 2;
  const size_t NEED   = HF_OFF + H_SZ;   // ~245.4 MB

  if (ws_size >= NEED) {
    __bf16* Xg = (__bf16*)(ws + XG_OFF);
    __bf16* Wt = (__bf16*)(ws + WT_OFF);
    __bf16* H  = (__bf16*)(ws + HF_OFF);

    k_init<<<(Tpad + 255) / 256, 256, 0, stream>>>(counts, cursors, bucket, Tpad);
    k_hist<<<(T_TOK + 255) / 256, 256, 0, stream>>>(EI, counts);
    k_scan<<<1, 64, 0, stream>>>(counts, po);
    k_scatter<<<(T_TOK + 255) / 256, 256, 0, stream>>>(EI, po, cursors, bucket);
    k_gather<<<Tpad, 256, 0, stream>>>(X, bucket, Xg);
    k_transpose<<<dim3(DFF / 64, DMODEL / 64, NEXP), 256, 0, stream>>>(W1, Wt, DMODEL, DFF);
    k_gemm1b<<<(Tpad / BM) * (DFF / BN), 256, 0, stream>>>(Xg, Wt, b1, po, H);
    k_transpose<<<dim3(DMODEL / 64, DFF / 64, NEXP), 256, 0, stream>>>(W2, Wt, DFF, DMODEL);
    k_gemm2b<<<(Tpad / BM) * (DMODEL / BN), 256, 0, stream>>>(H, Wt, b2, bucket, po, out);
    return;
  }

  // ---- round-1 fallback path ----
  const size_t H_OFF = 512 + (size_t)Tpad * 4;
  __bf16* H = (__bf16*)(ws + H_OFF);
  size_t avail = (ws_size > H_OFF) ? ws_size - H_OFF : 0;
  long long crll = (long long)(avail / ((size_t)DFF * 2));
  int CR = (crll > Tpad) ? Tpad : (int)crll;
  CR -= CR % BM;
  if (CR < BM) {
    k_fallback<<<T_TOK, 256, 0, stream>>>(X, EI, W1, b1, W2, b2, out);
    return;
  }
  k_init<<<(Tpad + 255) / 256, 256, 0, stream>>>(counts, cursors, bucket, Tpad);
  k_hist<<<(T_TOK + 255) / 256, 256, 0, stream>>>(EI, counts);
  k_scan<<<1, 64, 0, stream>>>(counts, po);
  k_scatter<<<(T_TOK + 255) / 256, 256, 0, stream>>>(EI, po, cursors, bucket);
  int nchunks = (Tpad + CR - 1) / CR;
  for (int c = 0; c < nchunks; c++) {
    int base = c * CR;
    int rows = Tpad - base; if (rows > CR) rows = CR;
    int mt = rows / BM;
    k_gemm1<<<dim3(mt, DFF / BN), 256, 0, stream>>>(X, W1, b1, bucket, po, H, base);
    k_gemm2<<<dim3(mt, DMODEL / BN), 256, 0, stream>>>(H, W2, b2, bucket, po, out, base);
  }
}